// Round 3
// baseline (657.193 us; speedup 1.0000x reference)
//
#include <hip/hip_runtime.h>

#define W 64
#define D 256
#define NH 8

typedef unsigned short u16;
typedef __attribute__((ext_vector_type(8))) short bf16x8;
typedef __attribute__((ext_vector_type(4))) float f32x4;

__device__ __forceinline__ u16 f2bf(float f) {
    union { float f; unsigned u; } v; v.f = f;
    unsigned r = v.u + 0x7fffu + ((v.u >> 16) & 1u);
    return (u16)(r >> 16);
}

// ---------------- LDS layout (bytes) ----------------
// xs : [64][264] u16  x staging (bf16, padded); later aliased by attn_out   33792
// qk : [8 heads][64 tok][72] u16 (cols 0..31 q, 32..63 k, 8 pad)            73728
// vT : [8 heads][32 d ][72] u16 (row=d, col=tok);                           36864
//      after vf regs loaded (barrier), vT region is aliased by P buffers
// total 144384
#define OFF_XS 0
#define XS_ROW 264
#define OFF_QK 33792
#define QK_ROW 72
#define OFF_VT 107520
#define VT_ROW 72
#define P_ROW  72

__global__ __launch_bounds__(1024, 4) void win_attn(
    const float* __restrict__ x, const float* __restrict__ bqkv,
    const float* __restrict__ bproj, const float* __restrict__ relb,
    const u16* __restrict__ wqkvT, const u16* __restrict__ wprojT,
    float* __restrict__ out)
{
    __shared__ __align__(16) char smem[144384];

    const int tid  = threadIdx.x;
    const int lane = tid & 63;
    const int wv   = tid >> 6;       // 0..15
    const int h    = wv & 7;         // head
    const int th   = wv >> 3;        // token half (rows th*32 .. th*32+31)
    const int l15  = lane & 15;
    const int g    = lane >> 4;
    const int w    = blockIdx.x;

    u16* xs = (u16*)(smem + OFF_XS);
    u16* qk = (u16*)(smem + OFF_QK);
    u16* vT = (u16*)(smem + OFF_VT);
    u16* Pb = (u16*)(smem + OFF_VT) + wv * 16 * P_ROW;   // aliases vT (after barrier)

    const f32x4 z4 = {0.f, 0.f, 0.f, 0.f};

    // ---------- Phase 0: stage x window -> LDS bf16 ----------
    // 64*256 = 16384 floats = 4096 float4; 1024 threads -> 4 float4 each.
    const float* xw = x + (size_t)w * (W * D);
    #pragma unroll
    for (int i = 0; i < 4; ++i) {
        int e   = i * 4096 + tid * 4;
        int row = e >> 8, col = e & 255;
        float4 v = *(const float4*)(xw + e);
        ushort4 b;
        b.x = f2bf(v.x); b.y = f2bf(v.y); b.z = f2bf(v.z); b.w = f2bf(v.w);
        *(ushort4*)(xs + row * XS_ROW + col) = b;
    }
    __syncthreads();

    // ---------- Phase 1: x A-fragments for this wave's 32 rows ----------
    bf16x8 afr[2][8];
    #pragma unroll
    for (int rt = 0; rt < 2; ++rt)
        #pragma unroll
        for (int ks = 0; ks < 8; ++ks)
            afr[rt][ks] = *(const bf16x8*)(xs + (th * 32 + 16 * rt + l15) * XS_ROW + ks * 32 + g * 8);

    // ---------- Phase 2: QKV GEMM (wave (h,th): head h cols, its 32 rows) ----------
    #pragma unroll
    for (int mc = 0; mc < 6; ++mc) {
        const int mat = mc >> 1, ct = mc & 1;           // mat: 0=q 1=k 2=v
        const int n0  = mat * 256 + h * 32 + ct * 16;
        const u16* brow = wqkvT + (size_t)(n0 + l15) * 256;
        f32x4 acc[2] = {z4, z4};
        #pragma unroll
        for (int ks = 0; ks < 8; ++ks) {
            bf16x8 bf = *(const bf16x8*)(brow + ks * 32 + g * 8);
            acc[0] = __builtin_amdgcn_mfma_f32_16x16x32_bf16(afr[0][ks], bf, acc[0], 0, 0, 0);
            acc[1] = __builtin_amdgcn_mfma_f32_16x16x32_bf16(afr[1][ks], bf, acc[1], 0, 0, 0);
        }
        const float bias = bqkv[n0 + l15];
        if (mat < 2) {   // q or k: [tok][d] per head
            u16* dst = qk + h * 64 * QK_ROW + mat * 32 + ct * 16 + l15;
            #pragma unroll
            for (int rt = 0; rt < 2; ++rt)
                #pragma unroll
                for (int r = 0; r < 4; ++r)
                    dst[(th * 32 + 16 * rt + 4 * g + r) * QK_ROW] = f2bf(acc[rt][r] + bias);
        } else {         // v transposed: [d][tok]
            u16* dst = vT + h * 32 * VT_ROW + (ct * 16 + l15) * VT_ROW;
            #pragma unroll
            for (int rt = 0; rt < 2; ++rt)
                #pragma unroll
                for (int r = 0; r < 4; ++r)
                    dst[th * 32 + 16 * rt + 4 * g + r] = f2bf(acc[rt][r] + bias);
        }
    }
    __syncthreads();   // full q,k,v for every head visible

    // ---------- Phase 3: attention. Wave (h,th) owns q-rows th*32..+31 ----------
    const u16* qbase = qk + h * 64 * QK_ROW;
    bf16x8 qf[2], kf[4], vf[2][2];
    #pragma unroll
    for (int t = 0; t < 2; ++t)
        qf[t] = *(const bf16x8*)(qbase + (th * 32 + 16 * t + l15) * QK_ROW + g * 8);
    #pragma unroll
    for (int t = 0; t < 4; ++t)
        kf[t] = *(const bf16x8*)(qbase + (16 * t + l15) * QK_ROW + 32 + g * 8);
    #pragma unroll
    for (int ks = 0; ks < 2; ++ks)
        #pragma unroll
        for (int cd = 0; cd < 2; ++cd)
            vf[ks][cd] = *(const bf16x8*)(vT + h * 32 * VT_ROW + (cd * 16 + l15) * VT_ROW + ks * 32 + g * 8);
    __syncthreads();   // vT consumed everywhere -> P may alias it

    const float* biasrow = relb + h * 127;
    const float scale = 0.17677669529663687f;   // 1/sqrt(32)
    u16* ao = xs;   // attn_out aliases dead x staging (xs last read in phase 1)

    #pragma unroll
    for (int rt = 0; rt < 2; ++rt) {
        f32x4 s[4];
        #pragma unroll
        for (int ct = 0; ct < 4; ++ct)
            s[ct] = __builtin_amdgcn_mfma_f32_16x16x32_bf16(qf[rt], kf[ct], z4, 0, 0, 0);

        float sv[4][4];   // [ct][r]
        #pragma unroll
        for (int ct = 0; ct < 4; ++ct) {
            const int k_tok = 16 * ct + l15;
            #pragma unroll
            for (int r = 0; r < 4; ++r) {
                const int q_tok = th * 32 + 16 * rt + 4 * g + r;
                sv[ct][r] = s[ct][r] * scale + biasrow[k_tok - q_tok + 63];
            }
        }
        #pragma unroll
        for (int r = 0; r < 4; ++r) {
            float m = fmaxf(fmaxf(sv[0][r], sv[1][r]), fmaxf(sv[2][r], sv[3][r]));
            #pragma unroll
            for (int mask = 1; mask <= 8; mask <<= 1)
                m = fmaxf(m, __shfl_xor(m, mask, 64));
            float e0 = __expf(sv[0][r] - m), e1 = __expf(sv[1][r] - m);
            float e2 = __expf(sv[2][r] - m), e3 = __expf(sv[3][r] - m);
            float sum = (e0 + e1) + (e2 + e3);
            #pragma unroll
            for (int mask = 1; mask <= 8; mask <<= 1)
                sum += __shfl_xor(sum, mask, 64);
            const float inv = 1.0f / sum;
            const int prow = 4 * g + r;
            Pb[prow * P_ROW +      l15] = f2bf(e0 * inv);
            Pb[prow * P_ROW + 16 + l15] = f2bf(e1 * inv);
            Pb[prow * P_ROW + 32 + l15] = f2bf(e2 * inv);
            Pb[prow * P_ROW + 48 + l15] = f2bf(e3 * inv);
        }
        bf16x8 pf0 = *(const bf16x8*)(Pb + l15 * P_ROW + g * 8);
        bf16x8 pf1 = *(const bf16x8*)(Pb + l15 * P_ROW + 32 + g * 8);
        #pragma unroll
        for (int cd = 0; cd < 2; ++cd) {
            f32x4 o = __builtin_amdgcn_mfma_f32_16x16x32_bf16(pf0, vf[0][cd], z4, 0, 0, 0);
            o = __builtin_amdgcn_mfma_f32_16x16x32_bf16(pf1, vf[1][cd], o, 0, 0, 0);
            #pragma unroll
            for (int r = 0; r < 4; ++r)
                ao[(th * 32 + 16 * rt + 4 * g + r) * XS_ROW + h * 32 + 16 * cd + l15] = f2bf(o[r]);
        }
    }
    __syncthreads();   // attn_out complete

    // ---------- Phase 4: output projection ----------
    // wave -> rows rowhalf*32 (2 tiles), cols colgrp*32 (2 tiles)
    const int rowhalf = wv & 1, colgrp = wv >> 1;
    bf16x8 pfr[2][8];
    #pragma unroll
    for (int rt = 0; rt < 2; ++rt)
        #pragma unroll
        for (int ks = 0; ks < 8; ++ks)
            pfr[rt][ks] = *(const bf16x8*)(xs + (rowhalf * 32 + 16 * rt + l15) * XS_ROW + ks * 32 + g * 8);

    f32x4 pacc[2][2] = {{z4, z4}, {z4, z4}};
    #pragma unroll
    for (int ct = 0; ct < 2; ++ct) {
        const u16* brow = wprojT + (size_t)(colgrp * 32 + ct * 16 + l15) * 256;
        #pragma unroll
        for (int ks = 0; ks < 8; ++ks) {
            bf16x8 bf = *(const bf16x8*)(brow + ks * 32 + g * 8);
            #pragma unroll
            for (int rt = 0; rt < 2; ++rt)
                pacc[ct][rt] = __builtin_amdgcn_mfma_f32_16x16x32_bf16(pfr[rt][ks], bf, pacc[ct][rt], 0, 0, 0);
        }
    }
    float* outw = out + (size_t)w * (W * D);
    #pragma unroll
    for (int ct = 0; ct < 2; ++ct) {
        const int n = colgrp * 32 + ct * 16 + l15;
        const float bp = bproj[n];
        #pragma unroll
        for (int rt = 0; rt < 2; ++rt)
            #pragma unroll
            for (int r = 0; r < 4; ++r)
                outw[(rowhalf * 32 + 16 * rt + 4 * g + r) * D + n] = pacc[ct][rt][r] + bp;
    }
}

// Transpose + bf16-convert the weight matrices into workspace (L2-resident).
__global__ void prep_weights(const float* __restrict__ wqkv, const float* __restrict__ wproj,
                             u16* __restrict__ wqkvT, u16* __restrict__ wprojT)
{
    int i = blockIdx.x * 256 + threadIdx.x;
    if (i < 768 * 256) {
        int n = i >> 8, k = i & 255;
        wqkvT[i] = f2bf(wqkv[k * 768 + n]);
    } else {
        int j = i - 768 * 256;
        int n = j >> 8, k = j & 255;
        wprojT[j] = f2bf(wproj[k * 256 + n]);
    }
}

extern "C" void kernel_launch(void* const* d_in, const int* in_sizes, int n_in,
                              void* d_out, int out_size, void* d_ws, size_t ws_size,
                              hipStream_t stream)
{
    const float* x     = (const float*)d_in[0];
    const float* wqkv  = (const float*)d_in[1];
    const float* bqkv  = (const float*)d_in[2];
    const float* wproj = (const float*)d_in[3];
    const float* bproj = (const float*)d_in[4];
    const float* relb  = (const float*)d_in[5];

    u16* wqkvT  = (u16*)d_ws;                 // 768*256 bf16
    u16* wprojT = wqkvT + 768 * 256;          // 256*256 bf16

    prep_weights<<<1024, 256, 0, stream>>>(wqkv, wproj, wqkvT, wprojT);

    const int nwin = in_sizes[0] / (W * D);   // 4096
    win_attn<<<nwin, 1024, 0, stream>>>(x, bqkv, bproj, relb, wqkvT, wprojT, (float*)d_out);
}